// Round 7
// baseline (285.575 us; speedup 1.0000x reference)
//
#include <hip/hip_runtime.h>

// ---------------- workspace layout (byte offsets, all 256-aligned) ----------
static constexpr size_t OFF_XT = 0;          // xT  [3][32][32][64] f32   786432 B
static constexpr size_t OFF_H1 = 786432;     // h1  [18][28][28][64]      3612672 B  (dead after k2; reused as h5b)
static constexpr size_t OFF_H2 = 4399104;    // h2  [51][14][14][64]      2558976 B
static constexpr size_t OFF_H3 = 6958080;    // h3  [255][5][5][2][2][64] 6528000 B  (pool-permuted)
static constexpr size_t OFF_H4 = 13486080;   // h4  [515][5][5][64]       3296000 B
static constexpr size_t OFF_H5 = 16782080;   // h5a [2500][64] PARTIAL    640000 B
static constexpr size_t OFF_H5B = OFF_H1;    // h5b [2500][64] PARTIAL    (aliases dead h1)
static constexpr size_t OFF_H6 = 17422080;   // h6T [120][64] PRE-ACT     30720 B (zeroed in k0; atomicAdd in k6)
static constexpr size_t OFF_M1 = 17474304;   // int src1[51][4]           1024 B
static constexpr size_t OFF_M2 = 17475328;   // Meta2[536]                8704 B
static constexpr size_t OFF_W2 = 17484032;   // float W2[536][51]         109568 B
// total ~17.6 MB

struct Meta2 { int g; int special; float wj; int valid; };

// enumerate pc1 groups in build_perm order (tiny: 51 entries, F=6 ncpf=3)
__device__ inline void scan_ijk(int F, int ncpf, int g, int& oi, int& oj, int& ok) {
  int cnt = 0;
  for (int i = 0; i < F; ++i)
    for (int j = 0; j < ncpf; ++j) {
      int ks = (j == 0) ? i : i + 1;
      for (int k = ks; k < F; ++k) {
        if (cnt == g) { oi = i; oj = j; ok = k; return; }
        ++cnt;
      }
    }
  oi = 0; oj = 0; ok = 0;
}

// K0: blocks 0..95   : transpose x [64][3][32][32] -> xT [3][32][32][64]
//     block  96      : pc1 gather metadata (51 groups x 3 srcs)
//     blocks 97..203 : pc2 metadata + densified W2, one thread per (slot,p)
//     blocks 204..233: zero h6 (fc1 atomicAdd accumulator; replaces memset dispatch)
__global__ void k0_setup(const float* __restrict__ x, const float* __restrict__ pc2_w,
                         float* ws) {
  int bx = blockIdx.x, tid = threadIdx.x;
  if (bx < 96) {
    __shared__ float t[64][33];
    int c = bx >> 5, y = bx & 31;
    for (int r = 0; r < 8; ++r) {
      int b = r * 8 + (tid >> 5), xx = tid & 31;
      t[b][xx] = x[((b * 3 + c) * 32 + y) * 32 + xx];
    }
    __syncthreads();
    float* xT = ws + OFF_XT / 4;
    for (int r = 0; r < 8; ++r) {
      int xx = r * 4 + (tid >> 6), b = tid & 63;
      xT[((c * 32 + y) * 32 + xx) * 64 + b] = t[b][xx];
    }
  } else if (bx == 96) {
    if (tid < 51) {
      int i, j, k; scan_ijk(6, 3, tid, i, j, k);
      int* src1 = (int*)((char*)ws + OFF_M1);
      for (int p = 0; p < 3; ++p)
        src1[tid * 4 + p] = (p == j) ? (i * 3 + j) : (k * 3 + p);
    }
  } else if (bx < 204) {
    int idx = (bx - 97) * 256 + tid;     // one thread per (s,p), 536*51 = 27336
    if (idx < 536 * 51) {
      int s = idx / 51, p = idx - s * 51;
      int k, base;
      if (s < 8)        { k = 0; base = 0; }
      else if (s < 64)  { k = 1; base = 8; }
      else if (s < 168) { k = 2; base = 64; }
      else if (s < 328) { k = 3; base = 168; }
      else              { k = 4; base = 328; }
      int id2 = s - base;
      int cnt = 51 * k + 1;              // groups using contiguous block k
      Meta2* m2 = (Meta2*)((char*)ws + OFF_M2);
      float* W2 = (float*)((char*)ws + OFF_W2);
      if (id2 < cnt) {
        int i, j;
        if (id2 <= k) { i = id2; j = 0; }
        else { int t2 = id2 - (k + 1); i = t2 / 50; j = t2 - i * 50 + 1; }
        int off = 205 * i - 51 * ((i * (i - 1)) >> 1);
        int g = (j == 0) ? (off + (k - i))
                         : (off + (5 - i) + (j - 1) * (4 - i) + (k - i - 1));
        W2[s * 51 + p] = (p == j) ? 0.f : pc2_w[g * 51 + p];
        if (p == 0) {
          m2[s].g = g; m2[s].special = i * 51 + j;
          m2[s].wj = pc2_w[g * 51 + j]; m2[s].valid = 1;
        }
      } else {
        W2[s * 51 + p] = 0.f;
        if (p == 0) { m2[s].g = 0; m2[s].special = 0; m2[s].wj = 0.f; m2[s].valid = 0; }
      }
    }
  } else {
    int idx = (bx - 204) * 256 + tid;    // zero h6: 120*64 = 7680 floats
    if (idx < 7680) (ws + OFF_H6 / 4)[idx] = 0.f;
  }
}

// K1: dw1 5x5, groups=3 (c_in = o/6). grid(196,18) block(64,4), lane=batch
__global__ void k1_dw1(const float* __restrict__ w, const float* __restrict__ bias,
                       float* ws) {
  const float* xT = ws + OFF_XT / 4;
  float* h1 = ws + OFF_H1 / 4;
  int b = threadIdx.x;
  int pos = blockIdx.x * 4 + threadIdx.y;   // 0..783
  int o = blockIdx.y;
  int y = pos / 28, xo = pos % 28;
  int c = o / 6;
  float acc = bias[o];
  #pragma unroll
  for (int ky = 0; ky < 5; ++ky)
    #pragma unroll
    for (int kx = 0; kx < 5; ++kx)
      acc = fmaf(xT[((c * 32 + y + ky) * 32 + xo + kx) * 64 + b],
                 w[o * 25 + ky * 5 + kx], acc);
  h1[((o * 28 + y) * 28 + xo) * 64 + b] = acc;
}

// K2: pc1 gather (3 taps) + bias + relu + 2x2 maxpool. grid(49,51) block(64,4)
__global__ void k2_pc1(const float* __restrict__ w, const float* __restrict__ bias,
                       float* ws) {
  const float* h1 = ws + OFF_H1 / 4;
  const int* src1 = (const int*)((const char*)ws + OFF_M1);
  float* h2 = ws + OFF_H2 / 4;
  int b = threadIdx.x;
  int pos = blockIdx.x * 4 + threadIdx.y;   // 0..195 pooled positions
  int g = blockIdx.y;
  int py = pos / 14, px = pos % 14;
  int s0 = src1[g * 4 + 0], s1 = src1[g * 4 + 1], s2 = src1[g * 4 + 2];
  float w0 = w[g * 3 + 0], w1 = w[g * 3 + 1], w2 = w[g * 3 + 2], bb = bias[g];
  float m = 0.f;  // relu folds into max with 0 init
  #pragma unroll
  for (int dy = 0; dy < 2; ++dy)
    #pragma unroll
    for (int dx = 0; dx < 2; ++dx) {
      int y = py * 2 + dy, xx = px * 2 + dx;
      float a = bb;
      a = fmaf(h1[((s0 * 28 + y) * 28 + xx) * 64 + b], w0, a);
      a = fmaf(h1[((s1 * 28 + y) * 28 + xx) * 64 + b], w1, a);
      a = fmaf(h1[((s2 * 28 + y) * 28 + xx) * 64 + b], w2, a);
      m = fmaxf(m, a);
    }
  h2[((g * 14 + py) * 14 + px) * 64 + b] = m;
}

// K3: dw2 5x5, groups=51 (c_in = o/5), writes pool-permuted h3. grid(25,255) block(64,4)
__global__ void k3_dw2(const float* __restrict__ w, const float* __restrict__ bias,
                       float* ws) {
  const float* h2 = ws + OFF_H2 / 4;
  float* h3 = ws + OFF_H3 / 4;
  int b = threadIdx.x;
  int pos = blockIdx.x * 4 + threadIdx.y;   // 0..99
  int o = blockIdx.y;
  int y = pos / 10, xo = pos % 10;
  int c = o / 5;
  float acc = bias[o];
  #pragma unroll
  for (int ky = 0; ky < 5; ++ky)
    #pragma unroll
    for (int kx = 0; kx < 5; ++kx)
      acc = fmaf(h2[((c * 14 + y + ky) * 14 + xo + kx) * 64 + b],
                 w[o * 25 + ky * 5 + kx], acc);
  int py = y >> 1, dy = y & 1, px = xo >> 1, dx = xo & 1;
  h3[((o * 25 + py * 5 + px) * 4 + dy * 2 + dx) * 64 + b] = acc;
}

// K4: pc2 = dense 51-dot over contiguous block k + rank-1 correction, then
//     bias + relu + pool. block(64,4): 4 waves share pyx (activation loads
//     L1-hit), each wave owns 2 slots. wv is readfirstlane-scalarized so the
//     weight/meta addresses stay wave-uniform s_loads (R5's raw threadIdx.y
//     defeated LLVM's uniformity analysis -> per-lane global_loads).
__global__ void __launch_bounds__(256) k4_pc2(const float* __restrict__ bias, float* ws) {
  const float* h3 = ws + OFF_H3 / 4;
  const float* W2 = (const float*)((const char*)ws + OFF_W2);
  const Meta2* m2 = (const Meta2*)((const char*)ws + OFF_M2);
  float* h4 = ws + OFF_H4 / 4;
  int b = threadIdx.x;
  int wv = __builtin_amdgcn_readfirstlane(threadIdx.y);  // scalar wave id
  int pyx = blockIdx.x;          // pooled position, 0..24
  int chunk = blockIdx.y;        // 0..66
  int k;
  if (chunk < 1) k = 0; else if (chunk < 8) k = 1; else if (chunk < 21) k = 2;
  else if (chunk < 41) k = 3; else k = 4;
  int s0 = chunk * 8 + wv * 2;   // this wave's 2 slots (scalar)
  float acc[2][4];
  #pragma unroll
  for (int m = 0; m < 2; ++m)
    #pragma unroll
    for (int q = 0; q < 4; ++q) acc[m][q] = 0.f;
  const float* hb = h3 + (size_t)(k * 51 * 100 + pyx * 4) * 64 + b;  // ch stride 6400
  const float* wr0 = W2 + (s0 + 0) * 51;
  const float* wr1 = W2 + (s0 + 1) * 51;
  for (int p = 0; p < 51; ++p) {
    float v0 = hb[p * 6400 + 0];
    float v1 = hb[p * 6400 + 64];
    float v2 = hb[p * 6400 + 128];
    float v3 = hb[p * 6400 + 192];
    float wa = wr0[p], wb = wr1[p];     // scalar s_loads
    acc[0][0] = fmaf(v0, wa, acc[0][0]);
    acc[0][1] = fmaf(v1, wa, acc[0][1]);
    acc[0][2] = fmaf(v2, wa, acc[0][2]);
    acc[0][3] = fmaf(v3, wa, acc[0][3]);
    acc[1][0] = fmaf(v0, wb, acc[1][0]);
    acc[1][1] = fmaf(v1, wb, acc[1][1]);
    acc[1][2] = fmaf(v2, wb, acc[1][2]);
    acc[1][3] = fmaf(v3, wb, acc[1][3]);
  }
  #pragma unroll
  for (int m = 0; m < 2; ++m) {
    Meta2 mm = m2[s0 + m];
    if (!mm.valid) continue;             // scalar branch
    const float* hs = h3 + (size_t)(mm.special * 100 + pyx * 4) * 64 + b;
    float bb = bias[mm.g];
    float r0 = fmaf(hs[0],   mm.wj, acc[m][0]) + bb;
    float r1 = fmaf(hs[64],  mm.wj, acc[m][1]) + bb;
    float r2 = fmaf(hs[128], mm.wj, acc[m][2]) + bb;
    float r3 = fmaf(hs[192], mm.wj, acc[m][3]) + bb;
    float r = fmaxf(fmaxf(r0, r1), fmaxf(r2, r3));
    h4[(mm.g * 25 + pyx) * 64 + b] = fmaxf(r, 0.f);
  }
}

// K5: oo partials (515->100). grid(25 pyx, 25 og, 2 ks) block(64,4).
//     base is readfirstlane-scalarized -> weight loads are batched s_loads
//     on the SMEM pipe (VMEM only carries the activation load).
__global__ void __launch_bounds__(256) k5_oo(const float* __restrict__ w, float* ws) {
  const float* h4 = ws + OFF_H4 / 4;
  __shared__ float red[4][4][64];
  int lane = threadIdx.x;
  int wv = __builtin_amdgcn_readfirstlane(threadIdx.y);
  int pyx = blockIdx.x, og = blockIdx.y, ks = blockIdx.z;
  int kb = ks ? 258 : 0;                 // K halves: [0,258) / [258,515)
  int kn = ks ? 257 : 258;
  int q = kn >> 2, r = kn & 3;
  int base = __builtin_amdgcn_readfirstlane(kb + wv * q + (wv < r ? wv : r));
  int n = q + (wv < r ? 1 : 0);          // 64..65 iters per wave
  const float* w0 = w + (og * 4 + 0) * 515;
  const float* w1 = w + (og * 4 + 1) * 515;
  const float* w2 = w + (og * 4 + 2) * 515;
  const float* w3 = w + (og * 4 + 3) * 515;
  const float* hp = h4 + pyx * 64 + lane;
  float a0 = 0.f, a1 = 0.f, a2 = 0.f, a3 = 0.f;
  #pragma unroll 4
  for (int i = 0; i < n; ++i) {
    int c = base + i;
    float v = hp[c * 1600];
    a0 = fmaf(v, w0[c], a0);
    a1 = fmaf(v, w1[c], a1);
    a2 = fmaf(v, w2[c], a2);
    a3 = fmaf(v, w3[c], a3);
  }
  red[wv][0][lane] = a0; red[wv][1][lane] = a1;
  red[wv][2][lane] = a2; red[wv][3][lane] = a3;
  __syncthreads();
  if (wv == 0) {
    float* h5p = ws + (ks ? OFF_H5B : OFF_H5) / 4;
    #pragma unroll
    for (int m = 0; m < 4; ++m) {
      float s = red[0][m][lane] + red[1][m][lane] + red[2][m][lane] + red[3][m][lane];
      h5p[((og * 4 + m) * 25 + pyx) * 64 + lane] = s;
    }
  }
}

// K6: fc1 partials. grid(30,16) block(64,4): 16 k-slices. base scalarized ->
//     fc1 weight loads stay s_load-batched. Sums h5a+h5b, oo bias+relu inline;
//     LDS reduce; atomicAdd into PRE-ACT h6 (zeroed in k0).
__global__ void __launch_bounds__(256) k6_fc1(const float* __restrict__ w,
                                              const float* __restrict__ oo_b, float* ws) {
  const float* h5a = ws + OFF_H5 / 4;
  const float* h5b = ws + OFF_H5B / 4;
  float* h6 = ws + OFF_H6 / 4;
  __shared__ float red[4][4][64];
  int lane = threadIdx.x;
  int wv = __builtin_amdgcn_readfirstlane(threadIdx.y);
  int og = blockIdx.x, ks = blockIdx.y;
  int kb = ks * 156 + (ks < 4 ? ks : 4);       // block k-base
  int kn = 156 + (ks < 4 ? 1 : 0);             // block k-count (sums to 2500)
  int q = kn >> 2, r = kn & 3;
  int base = __builtin_amdgcn_readfirstlane(kb + wv * q + (wv < r ? wv : r));
  int n = q + (wv < r ? 1 : 0);                // wave k-count (~39)
  const float* w0 = w + (og * 4 + 0) * 2500;
  const float* w1 = w + (og * 4 + 1) * 2500;
  const float* w2 = w + (og * 4 + 2) * 2500;
  const float* w3 = w + (og * 4 + 3) * 2500;
  float a0 = 0.f, a1 = 0.f, a2 = 0.f, a3 = 0.f;
  #pragma unroll 4
  for (int i = 0; i < n; ++i) {
    int k = base + i;
    float v = fmaxf(h5a[k * 64 + lane] + h5b[k * 64 + lane] + oo_b[k / 25], 0.f);
    a0 = fmaf(v, w0[k], a0);
    a1 = fmaf(v, w1[k], a1);
    a2 = fmaf(v, w2[k], a2);
    a3 = fmaf(v, w3[k], a3);
  }
  red[wv][0][lane] = a0; red[wv][1][lane] = a1;
  red[wv][2][lane] = a2; red[wv][3][lane] = a3;
  __syncthreads();
  if (wv == 0) {
    #pragma unroll
    for (int m = 0; m < 4; ++m) {
      float s = red[0][m][lane] + red[1][m][lane] + red[2][m][lane] + red[3][m][lane];
      atomicAdd(&h6[(og * 4 + m) * 64 + lane], s);
    }
  }
}

// K7: fused tail fc2+fc3, register-resident (NOT the R5 LDS-serialized version).
//     One block(64,16). Each wave loads relu(h6+fc1_b) into 120 VGPRs (reads are
//     L2-hit, 16x redundancy is cheap), computes its fc2 outputs with scalar
//     weights, exchanges a7 through LDS once, then 10 waves compute fc3.
__global__ void __launch_bounds__(1024) k7_tail(const float* __restrict__ w2,
                                                const float* __restrict__ fc1_b,
                                                const float* __restrict__ b2,
                                                const float* __restrict__ w3,
                                                const float* __restrict__ b3,
                                                float* out, const float* ws) {
  const float* h6 = ws + OFF_H6 / 4;
  __shared__ float a7[84][64];    // relu(fc2 out)
  int lane = threadIdx.x;
  int wv = __builtin_amdgcn_readfirstlane(threadIdx.y);
  float a6r[120];
  #pragma unroll
  for (int i = 0; i < 120; ++i)
    a6r[i] = fmaxf(h6[i * 64 + lane] + fc1_b[i], 0.f);
  // fc2: 84 outputs over 16 waves, weights via s_load (o scalar)
  for (int o = wv; o < 84; o += 16) {
    float acc = b2[o];
    #pragma unroll
    for (int i = 0; i < 120; ++i)
      acc = fmaf(a6r[i], w2[o * 120 + i], acc);
    a7[o][lane] = fmaxf(acc, 0.f);
  }
  __syncthreads();
  // fc3: 10 outputs, waves 0..9
  if (wv < 10) {
    int o = wv;
    float acc = b3[o];
    #pragma unroll 12
    for (int i = 0; i < 84; ++i)
      acc = fmaf(a7[i][lane], w3[o * 84 + i], acc);
    out[lane * 10 + o] = acc;
  }
}

extern "C" void kernel_launch(void* const* d_in, const int* in_sizes, int n_in,
                              void* d_out, int out_size, void* d_ws, size_t ws_size,
                              hipStream_t stream) {
  const float* x     = (const float*)d_in[0];
  const float* dw1_w = (const float*)d_in[1];
  const float* dw1_b = (const float*)d_in[2];
  const float* pc1_w = (const float*)d_in[3];
  const float* pc1_b = (const float*)d_in[4];
  const float* dw2_w = (const float*)d_in[5];
  const float* dw2_b = (const float*)d_in[6];
  const float* pc2_w = (const float*)d_in[7];
  const float* pc2_b = (const float*)d_in[8];
  const float* oo_w  = (const float*)d_in[9];
  const float* oo_b  = (const float*)d_in[10];
  const float* fc1_w = (const float*)d_in[11];
  const float* fc1_b = (const float*)d_in[12];
  const float* fc2_w = (const float*)d_in[13];
  const float* fc2_b = (const float*)d_in[14];
  const float* fc3_w = (const float*)d_in[15];
  const float* fc3_b = (const float*)d_in[16];
  float* ws = (float*)d_ws;
  float* out = (float*)d_out;

  hipLaunchKernelGGL(k0_setup, dim3(234), dim3(256), 0, stream, x, pc2_w, ws);
  hipLaunchKernelGGL(k1_dw1, dim3(196, 18), dim3(64, 4), 0, stream, dw1_w, dw1_b, ws);
  hipLaunchKernelGGL(k2_pc1, dim3(49, 51), dim3(64, 4), 0, stream, pc1_w, pc1_b, ws);
  hipLaunchKernelGGL(k3_dw2, dim3(25, 255), dim3(64, 4), 0, stream, dw2_w, dw2_b, ws);
  hipLaunchKernelGGL(k4_pc2, dim3(25, 67), dim3(64, 4), 0, stream, pc2_b, ws);
  hipLaunchKernelGGL(k5_oo, dim3(25, 25, 2), dim3(64, 4), 0, stream, oo_w, ws);
  hipLaunchKernelGGL(k6_fc1, dim3(30, 16), dim3(64, 4), 0, stream, fc1_w, oo_b, ws);
  hipLaunchKernelGGL(k7_tail, dim3(1), dim3(64, 16), 0, stream,
                     fc2_w, fc1_b, fc2_b, fc3_w, fc3_b, out, ws);
}

// Round 8
// 150.685 us; speedup vs baseline: 1.8952x; 1.8952x over previous
//
#include <hip/hip_runtime.h>

// ---------------- workspace layout (byte offsets, all 256-aligned) ----------
static constexpr size_t OFF_XT = 0;          // xT  [3][32][32][64] f32   786432 B
static constexpr size_t OFF_H1 = 786432;     // h1  [18][28][28][64]      3612672 B  (dead after k2; reused as h5b)
static constexpr size_t OFF_H2 = 4399104;    // h2  [51][14][14][64]      2558976 B
static constexpr size_t OFF_H3 = 6958080;    // h3  [255][5][5][2][2][64] 6528000 B  (pool-permuted)
static constexpr size_t OFF_H4 = 13486080;   // h4  [515][5][5][64]       3296000 B
static constexpr size_t OFF_H5 = 16782080;   // h5a [2500][64] PARTIAL    640000 B
static constexpr size_t OFF_H5B = OFF_H1;    // h5b [2500][64] PARTIAL    (aliases dead h1)
static constexpr size_t OFF_H6 = 17422080;   // h6T [120][64] PRE-ACT     30720 B (zeroed in k0; atomicAdd in k6)
static constexpr size_t OFF_H7 = 17452800;   // h7T [84][64]              21504 B
static constexpr size_t OFF_M1 = 17474304;   // int src1[51][4]           1024 B
static constexpr size_t OFF_M2 = 17475328;   // Meta2[536]                8704 B
static constexpr size_t OFF_W2 = 17484032;   // float W2[536][51]         109568 B
// total ~17.6 MB

struct Meta2 { int g; int special; float wj; int valid; };

// enumerate pc1 groups in build_perm order (tiny: 51 entries, F=6 ncpf=3)
__device__ inline void scan_ijk(int F, int ncpf, int g, int& oi, int& oj, int& ok) {
  int cnt = 0;
  for (int i = 0; i < F; ++i)
    for (int j = 0; j < ncpf; ++j) {
      int ks = (j == 0) ? i : i + 1;
      for (int k = ks; k < F; ++k) {
        if (cnt == g) { oi = i; oj = j; ok = k; return; }
        ++cnt;
      }
    }
  oi = 0; oj = 0; ok = 0;
}

// K0: blocks 0..95   : transpose x [64][3][32][32] -> xT [3][32][32][64]
//     block  96      : pc1 gather metadata (51 groups x 3 srcs)
//     blocks 97..203 : pc2 metadata + densified W2, one thread per (slot,p)
//     blocks 204..233: zero h6 (fc1 atomicAdd accumulator; replaces memset dispatch)
__global__ void k0_setup(const float* __restrict__ x, const float* __restrict__ pc2_w,
                         float* ws) {
  int bx = blockIdx.x, tid = threadIdx.x;
  if (bx < 96) {
    __shared__ float t[64][33];
    int c = bx >> 5, y = bx & 31;
    for (int r = 0; r < 8; ++r) {
      int b = r * 8 + (tid >> 5), xx = tid & 31;
      t[b][xx] = x[((b * 3 + c) * 32 + y) * 32 + xx];
    }
    __syncthreads();
    float* xT = ws + OFF_XT / 4;
    for (int r = 0; r < 8; ++r) {
      int xx = r * 4 + (tid >> 6), b = tid & 63;
      xT[((c * 32 + y) * 32 + xx) * 64 + b] = t[b][xx];
    }
  } else if (bx == 96) {
    if (tid < 51) {
      int i, j, k; scan_ijk(6, 3, tid, i, j, k);
      int* src1 = (int*)((char*)ws + OFF_M1);
      for (int p = 0; p < 3; ++p)
        src1[tid * 4 + p] = (p == j) ? (i * 3 + j) : (k * 3 + p);
    }
  } else if (bx < 204) {
    int idx = (bx - 97) * 256 + tid;     // one thread per (s,p), 536*51 = 27336
    if (idx < 536 * 51) {
      int s = idx / 51, p = idx - s * 51;
      int k, base;
      if (s < 8)        { k = 0; base = 0; }
      else if (s < 64)  { k = 1; base = 8; }
      else if (s < 168) { k = 2; base = 64; }
      else if (s < 328) { k = 3; base = 168; }
      else              { k = 4; base = 328; }
      int id2 = s - base;
      int cnt = 51 * k + 1;              // groups using contiguous block k
      Meta2* m2 = (Meta2*)((char*)ws + OFF_M2);
      float* W2 = (float*)((char*)ws + OFF_W2);
      if (id2 < cnt) {
        int i, j;
        if (id2 <= k) { i = id2; j = 0; }
        else { int t2 = id2 - (k + 1); i = t2 / 50; j = t2 - i * 50 + 1; }
        int off = 205 * i - 51 * ((i * (i - 1)) >> 1);
        int g = (j == 0) ? (off + (k - i))
                         : (off + (5 - i) + (j - 1) * (4 - i) + (k - i - 1));
        W2[s * 51 + p] = (p == j) ? 0.f : pc2_w[g * 51 + p];
        if (p == 0) {
          m2[s].g = g; m2[s].special = i * 51 + j;
          m2[s].wj = pc2_w[g * 51 + j]; m2[s].valid = 1;
        }
      } else {
        W2[s * 51 + p] = 0.f;
        if (p == 0) { m2[s].g = 0; m2[s].special = 0; m2[s].wj = 0.f; m2[s].valid = 0; }
      }
    }
  } else {
    int idx = (bx - 204) * 256 + tid;    // zero h6: 120*64 = 7680 floats
    if (idx < 7680) (ws + OFF_H6 / 4)[idx] = 0.f;
  }
}

// K1: dw1 5x5, groups=3 (c_in = o/6). grid(196,18) block(64,4), lane=batch
__global__ void k1_dw1(const float* __restrict__ w, const float* __restrict__ bias,
                       float* ws) {
  const float* xT = ws + OFF_XT / 4;
  float* h1 = ws + OFF_H1 / 4;
  int b = threadIdx.x;
  int pos = blockIdx.x * 4 + threadIdx.y;   // 0..783
  int o = blockIdx.y;
  int y = pos / 28, xo = pos % 28;
  int c = o / 6;
  float acc = bias[o];
  #pragma unroll
  for (int ky = 0; ky < 5; ++ky)
    #pragma unroll
    for (int kx = 0; kx < 5; ++kx)
      acc = fmaf(xT[((c * 32 + y + ky) * 32 + xo + kx) * 64 + b],
                 w[o * 25 + ky * 5 + kx], acc);
  h1[((o * 28 + y) * 28 + xo) * 64 + b] = acc;
}

// K2: pc1 gather (3 taps) + bias + relu + 2x2 maxpool. grid(49,51) block(64,4)
__global__ void k2_pc1(const float* __restrict__ w, const float* __restrict__ bias,
                       float* ws) {
  const float* h1 = ws + OFF_H1 / 4;
  const int* src1 = (const int*)((const char*)ws + OFF_M1);
  float* h2 = ws + OFF_H2 / 4;
  int b = threadIdx.x;
  int pos = blockIdx.x * 4 + threadIdx.y;   // 0..195 pooled positions
  int g = blockIdx.y;
  int py = pos / 14, px = pos % 14;
  int s0 = src1[g * 4 + 0], s1 = src1[g * 4 + 1], s2 = src1[g * 4 + 2];
  float w0 = w[g * 3 + 0], w1 = w[g * 3 + 1], w2 = w[g * 3 + 2], bb = bias[g];
  float m = 0.f;  // relu folds into max with 0 init
  #pragma unroll
  for (int dy = 0; dy < 2; ++dy)
    #pragma unroll
    for (int dx = 0; dx < 2; ++dx) {
      int y = py * 2 + dy, xx = px * 2 + dx;
      float a = bb;
      a = fmaf(h1[((s0 * 28 + y) * 28 + xx) * 64 + b], w0, a);
      a = fmaf(h1[((s1 * 28 + y) * 28 + xx) * 64 + b], w1, a);
      a = fmaf(h1[((s2 * 28 + y) * 28 + xx) * 64 + b], w2, a);
      m = fmaxf(m, a);
    }
  h2[((g * 14 + py) * 14 + px) * 64 + b] = m;
}

// K3: dw2 5x5, groups=51 (c_in = o/5), writes pool-permuted h3. grid(25,255) block(64,4)
__global__ void k3_dw2(const float* __restrict__ w, const float* __restrict__ bias,
                       float* ws) {
  const float* h2 = ws + OFF_H2 / 4;
  float* h3 = ws + OFF_H3 / 4;
  int b = threadIdx.x;
  int pos = blockIdx.x * 4 + threadIdx.y;   // 0..99
  int o = blockIdx.y;
  int y = pos / 10, xo = pos % 10;
  int c = o / 5;
  float acc = bias[o];
  #pragma unroll
  for (int ky = 0; ky < 5; ++ky)
    #pragma unroll
    for (int kx = 0; kx < 5; ++kx)
      acc = fmaf(h2[((c * 14 + y + ky) * 14 + xo + kx) * 64 + b],
                 w[o * 25 + ky * 5 + kx], acc);
  int py = y >> 1, dy = y & 1, px = xo >> 1, dx = xo & 1;
  h3[((o * 25 + py * 5 + px) * 4 + dy * 2 + dx) * 64 + b] = acc;
}

// K4: pc2 = dense 51-dot over contiguous block k + rank-1 correction, then
//     bias + relu + pool. block(64,4): 4 waves share pyx (activation loads
//     L1-hit), each wave owns 2 slots, wv readfirstlane-scalarized (keeps
//     weight/meta addresses wave-uniform s_loads). Proven −~30 µs in R7.
__global__ void __launch_bounds__(256) k4_pc2(const float* __restrict__ bias, float* ws) {
  const float* h3 = ws + OFF_H3 / 4;
  const float* W2 = (const float*)((const char*)ws + OFF_W2);
  const Meta2* m2 = (const Meta2*)((const char*)ws + OFF_M2);
  float* h4 = ws + OFF_H4 / 4;
  int b = threadIdx.x;
  int wv = __builtin_amdgcn_readfirstlane(threadIdx.y);  // scalar wave id
  int pyx = blockIdx.x;          // pooled position, 0..24
  int chunk = blockIdx.y;        // 0..66
  int k;
  if (chunk < 1) k = 0; else if (chunk < 8) k = 1; else if (chunk < 21) k = 2;
  else if (chunk < 41) k = 3; else k = 4;
  int s0 = chunk * 8 + wv * 2;   // this wave's 2 slots (scalar)
  float acc[2][4];
  #pragma unroll
  for (int m = 0; m < 2; ++m)
    #pragma unroll
    for (int q = 0; q < 4; ++q) acc[m][q] = 0.f;
  const float* hb = h3 + (size_t)(k * 51 * 100 + pyx * 4) * 64 + b;  // ch stride 6400
  const float* wr0 = W2 + (s0 + 0) * 51;
  const float* wr1 = W2 + (s0 + 1) * 51;
  for (int p = 0; p < 51; ++p) {
    float v0 = hb[p * 6400 + 0];
    float v1 = hb[p * 6400 + 64];
    float v2 = hb[p * 6400 + 128];
    float v3 = hb[p * 6400 + 192];
    float wa = wr0[p], wb = wr1[p];     // scalar s_loads
    acc[0][0] = fmaf(v0, wa, acc[0][0]);
    acc[0][1] = fmaf(v1, wa, acc[0][1]);
    acc[0][2] = fmaf(v2, wa, acc[0][2]);
    acc[0][3] = fmaf(v3, wa, acc[0][3]);
    acc[1][0] = fmaf(v0, wb, acc[1][0]);
    acc[1][1] = fmaf(v1, wb, acc[1][1]);
    acc[1][2] = fmaf(v2, wb, acc[1][2]);
    acc[1][3] = fmaf(v3, wb, acc[1][3]);
  }
  #pragma unroll
  for (int m = 0; m < 2; ++m) {
    Meta2 mm = m2[s0 + m];
    if (!mm.valid) continue;             // scalar branch
    const float* hs = h3 + (size_t)(mm.special * 100 + pyx * 4) * 64 + b;
    float bb = bias[mm.g];
    float r0 = fmaf(hs[0],   mm.wj, acc[m][0]) + bb;
    float r1 = fmaf(hs[64],  mm.wj, acc[m][1]) + bb;
    float r2 = fmaf(hs[128], mm.wj, acc[m][2]) + bb;
    float r3 = fmaf(hs[192], mm.wj, acc[m][3]) + bb;
    float r = fmaxf(fmaxf(r0, r1), fmaxf(r2, r3));
    h4[(mm.g * 25 + pyx) * 64 + b] = fmaxf(r, 0.f);
  }
}

// K5: oo partials (515->100). grid(25 pyx, 25 og, 2 ks) block(64,4).
//     base readfirstlane-scalarized -> weight loads batched s_loads.
__global__ void __launch_bounds__(256) k5_oo(const float* __restrict__ w, float* ws) {
  const float* h4 = ws + OFF_H4 / 4;
  __shared__ float red[4][4][64];
  int lane = threadIdx.x;
  int wv = __builtin_amdgcn_readfirstlane(threadIdx.y);
  int pyx = blockIdx.x, og = blockIdx.y, ks = blockIdx.z;
  int kb = ks ? 258 : 0;                 // K halves: [0,258) / [258,515)
  int kn = ks ? 257 : 258;
  int q = kn >> 2, r = kn & 3;
  int base = __builtin_amdgcn_readfirstlane(kb + wv * q + (wv < r ? wv : r));
  int n = q + (wv < r ? 1 : 0);          // 64..65 iters per wave
  const float* w0 = w + (og * 4 + 0) * 515;
  const float* w1 = w + (og * 4 + 1) * 515;
  const float* w2 = w + (og * 4 + 2) * 515;
  const float* w3 = w + (og * 4 + 3) * 515;
  const float* hp = h4 + pyx * 64 + lane;
  float a0 = 0.f, a1 = 0.f, a2 = 0.f, a3 = 0.f;
  #pragma unroll 4
  for (int i = 0; i < n; ++i) {
    int c = base + i;
    float v = hp[c * 1600];
    a0 = fmaf(v, w0[c], a0);
    a1 = fmaf(v, w1[c], a1);
    a2 = fmaf(v, w2[c], a2);
    a3 = fmaf(v, w3[c], a3);
  }
  red[wv][0][lane] = a0; red[wv][1][lane] = a1;
  red[wv][2][lane] = a2; red[wv][3][lane] = a3;
  __syncthreads();
  if (wv == 0) {
    float* h5p = ws + (ks ? OFF_H5B : OFF_H5) / 4;
    #pragma unroll
    for (int m = 0; m < 4; ++m) {
      float s = red[0][m][lane] + red[1][m][lane] + red[2][m][lane] + red[3][m][lane];
      h5p[((og * 4 + m) * 25 + pyx) * 64 + lane] = s;
    }
  }
}

// K6: fc1 partials. grid(30,16) block(64,4): 16 k-slices, base scalarized.
//     Sums h5a+h5b, oo bias+relu inline; LDS reduce; atomicAdd into h6.
__global__ void __launch_bounds__(256) k6_fc1(const float* __restrict__ w,
                                              const float* __restrict__ oo_b, float* ws) {
  const float* h5a = ws + OFF_H5 / 4;
  const float* h5b = ws + OFF_H5B / 4;
  float* h6 = ws + OFF_H6 / 4;
  __shared__ float red[4][4][64];
  int lane = threadIdx.x;
  int wv = __builtin_amdgcn_readfirstlane(threadIdx.y);
  int og = blockIdx.x, ks = blockIdx.y;
  int kb = ks * 156 + (ks < 4 ? ks : 4);       // block k-base
  int kn = 156 + (ks < 4 ? 1 : 0);             // block k-count (sums to 2500)
  int q = kn >> 2, r = kn & 3;
  int base = __builtin_amdgcn_readfirstlane(kb + wv * q + (wv < r ? wv : r));
  int n = q + (wv < r ? 1 : 0);                // wave k-count (~39)
  const float* w0 = w + (og * 4 + 0) * 2500;
  const float* w1 = w + (og * 4 + 1) * 2500;
  const float* w2 = w + (og * 4 + 2) * 2500;
  const float* w3 = w + (og * 4 + 3) * 2500;
  float a0 = 0.f, a1 = 0.f, a2 = 0.f, a3 = 0.f;
  #pragma unroll 4
  for (int i = 0; i < n; ++i) {
    int k = base + i;
    float v = fmaxf(h5a[k * 64 + lane] + h5b[k * 64 + lane] + oo_b[k / 25], 0.f);
    a0 = fmaf(v, w0[k], a0);
    a1 = fmaf(v, w1[k], a1);
    a2 = fmaf(v, w2[k], a2);
    a3 = fmaf(v, w3[k], a3);
  }
  red[wv][0][lane] = a0; red[wv][1][lane] = a1;
  red[wv][2][lane] = a2; red[wv][3][lane] = a3;
  __syncthreads();
  if (wv == 0) {
    #pragma unroll
    for (int m = 0; m < 4; ++m) {
      float s = red[0][m][lane] + red[1][m][lane] + red[2][m][lane] + red[3][m][lane];
      atomicAdd(&h6[(og * 4 + m) * 64 + lane], s);
    }
  }
}

// K7: fc2 (120->84) + relu; applies relu(h6+fc1_b) inline. grid(84) block(256),
//     4-wave split-K + LDS reduce. (Fused tails failed twice: R5 LDS-serialized
//     on one CU = +24 µs; R7 register-resident spilled a6r[120] to scratch at
//     __launch_bounds__(1024) = +150 µs. Keep the split kernels.)
__global__ void __launch_bounds__(256) k7_fc2(const float* __restrict__ w,
                                              const float* __restrict__ fc1_b,
                                              const float* __restrict__ bias, float* ws) {
  const float* h6 = ws + OFF_H6 / 4;
  float* h7 = ws + OFF_H7 / 4;
  __shared__ float red[4][64];
  int lane = threadIdx.x & 63, wv = threadIdx.x >> 6;
  int o = blockIdx.x;
  float acc = 0.f;
  int i0 = wv * 30;
  #pragma unroll 5
  for (int i = i0; i < i0 + 30; ++i) {
    float v = fmaxf(h6[i * 64 + lane] + fc1_b[i], 0.f);
    acc = fmaf(v, w[o * 120 + i], acc);
  }
  red[wv][lane] = acc;
  __syncthreads();
  if (threadIdx.x < 64) {
    float s = red[0][lane] + red[1][lane] + red[2][lane] + red[3][lane] + bias[o];
    h7[o * 64 + lane] = fmaxf(s, 0.f);
  }
}

// K8: fc3 (84->10), writes d_out [64][10]. grid(10) block(256), 4-wave split-K.
__global__ void __launch_bounds__(256) k8_fc3(const float* __restrict__ w,
                                              const float* __restrict__ bias,
                                              float* out, const float* ws) {
  const float* h7 = ws + OFF_H7 / 4;
  __shared__ float red[4][64];
  int lane = threadIdx.x & 63, wv = threadIdx.x >> 6;
  int o = blockIdx.x;
  float acc = 0.f;
  int i0 = wv * 21;
  #pragma unroll 7
  for (int i = i0; i < i0 + 21; ++i)
    acc = fmaf(h7[i * 64 + lane], w[o * 84 + i], acc);
  red[wv][lane] = acc;
  __syncthreads();
  if (threadIdx.x < 64) {
    float s = red[0][lane] + red[1][lane] + red[2][lane] + red[3][lane] + bias[o];
    out[lane * 10 + o] = s;
  }
}

extern "C" void kernel_launch(void* const* d_in, const int* in_sizes, int n_in,
                              void* d_out, int out_size, void* d_ws, size_t ws_size,
                              hipStream_t stream) {
  const float* x     = (const float*)d_in[0];
  const float* dw1_w = (const float*)d_in[1];
  const float* dw1_b = (const float*)d_in[2];
  const float* pc1_w = (const float*)d_in[3];
  const float* pc1_b = (const float*)d_in[4];
  const float* dw2_w = (const float*)d_in[5];
  const float* dw2_b = (const float*)d_in[6];
  const float* pc2_w = (const float*)d_in[7];
  const float* pc2_b = (const float*)d_in[8];
  const float* oo_w  = (const float*)d_in[9];
  const float* oo_b  = (const float*)d_in[10];
  const float* fc1_w = (const float*)d_in[11];
  const float* fc1_b = (const float*)d_in[12];
  const float* fc2_w = (const float*)d_in[13];
  const float* fc2_b = (const float*)d_in[14];
  const float* fc3_w = (const float*)d_in[15];
  const float* fc3_b = (const float*)d_in[16];
  float* ws = (float*)d_ws;
  float* out = (float*)d_out;

  hipLaunchKernelGGL(k0_setup, dim3(234), dim3(256), 0, stream, x, pc2_w, ws);
  hipLaunchKernelGGL(k1_dw1, dim3(196, 18), dim3(64, 4), 0, stream, dw1_w, dw1_b, ws);
  hipLaunchKernelGGL(k2_pc1, dim3(49, 51), dim3(64, 4), 0, stream, pc1_w, pc1_b, ws);
  hipLaunchKernelGGL(k3_dw2, dim3(25, 255), dim3(64, 4), 0, stream, dw2_w, dw2_b, ws);
  hipLaunchKernelGGL(k4_pc2, dim3(25, 67), dim3(64, 4), 0, stream, pc2_b, ws);
  hipLaunchKernelGGL(k5_oo, dim3(25, 25, 2), dim3(64, 4), 0, stream, oo_w, ws);
  hipLaunchKernelGGL(k6_fc1, dim3(30, 16), dim3(64, 4), 0, stream, fc1_w, oo_b, ws);
  hipLaunchKernelGGL(k7_fc2, dim3(84), dim3(256), 0, stream, fc2_w, fc1_b, fc2_b, ws);
  hipLaunchKernelGGL(k8_fc3, dim3(10), dim3(256), 0, stream, fc3_w, fc3_b, out, ws);
}